// Round 1
// baseline (408.626 us; speedup 1.0000x reference)
//
#include <hip/hip_runtime.h>

#define NL 4096   // 64*64 low-res pixels
#define HH 32
#define WH 32

// ---------------------------------------------------------------------------
// Bilinear 2x upsample (half-pixel, border-clamped), [B,256,32,32]->[B,256,64,64]
// ---------------------------------------------------------------------------
__global__ __launch_bounds__(256) void upsample_k(const float* __restrict__ hf,
                                                  float* __restrict__ hu) {
  int idx = blockIdx.x * 256 + threadIdx.x;   // over 2*256*4096
  int n  = idx & (NL - 1);
  int bc = idx >> 12;                         // b*256 + c
  int y = n >> 6, x = n & 63;
  float sx = x * 0.5f - 0.25f;
  float sy = y * 0.5f - 0.25f;
  float x0f = floorf(sx), y0f = floorf(sy);
  float wx = sx - x0f, wy = sy - y0f;
  int x0 = (int)x0f, y0 = (int)y0f;
  int x0c = min(WH - 1, max(0, x0)), x1c = min(WH - 1, max(0, x0 + 1));
  int y0c = min(HH - 1, max(0, y0)), y1c = min(HH - 1, max(0, y0 + 1));
  const float* f = hf + (size_t)bc * (HH * WH);
  float v00 = f[y0c * WH + x0c], v01 = f[y0c * WH + x1c];
  float v10 = f[y1c * WH + x0c], v11 = f[y1c * WH + x1c];
  hu[idx] = (1.f - wy) * ((1.f - wx) * v00 + wx * v01)
          +        wy  * ((1.f - wx) * v10 + wx * v11);
}

// ---------------------------------------------------------------------------
// 1x1-conv GEMM: Y[b][o][n] = sum_k W[o][k] * X[b][k][n] (+bias) (+BN+ReLU)
// X may be a channel-concat of X1 (K1 ch) and X2 (K2 ch).
// TR: store pixel-major Y[b][n][o] instead of channel-major.
// Block (32,8): each thread: 2 consecutive n, J=OT/8 output channels.
// Grid: (B*64, M/OT).
// ---------------------------------------------------------------------------
template <int M, int K1, int K2, int OT, bool BN, bool TR>
__global__ __launch_bounds__(256) void gemm_k(
    const float* __restrict__ Wt, const float* __restrict__ bias,
    const float* __restrict__ X1, const float* __restrict__ X2,
    float* __restrict__ Y,
    const float* __restrict__ gamma, const float* __restrict__ beta,
    const float* __restrict__ rmean, const float* __restrict__ rvar) {
  constexpr int K = K1 + K2;
  constexpr int J = OT / 8;
  const int tx = threadIdx.x;                  // 0..31
  const int ty = threadIdx.y;                  // 0..7
  const int b = blockIdx.x >> 6;               // 64 n-tiles per batch
  const int n = ((blockIdx.x & 63) << 6) + tx * 2;
  const int obase = blockIdx.y * OT + ty;      // o = obase + 8*j

  float acc[2 * J];
#pragma unroll
  for (int i = 0; i < 2 * J; i++) acc[i] = 0.f;

  const float* w0 = Wt + (size_t)obase * K;
  {
    const float* x = X1 + (size_t)b * K1 * NL + n;
    for (int k = 0; k < K1; k += 4) {
      float4 wv[J];
#pragma unroll
      for (int j = 0; j < J; j++)
        wv[j] = *(const float4*)(w0 + (size_t)(8 * j) * K + k);
#pragma unroll
      for (int kk = 0; kk < 4; kk++) {
        float2 xv = *(const float2*)(x + (size_t)(k + kk) * NL);
#pragma unroll
        for (int j = 0; j < J; j++) {
          float wk = reinterpret_cast<const float*>(&wv[j])[kk];
          acc[2 * j]     = fmaf(wk, xv.x, acc[2 * j]);
          acc[2 * j + 1] = fmaf(wk, xv.y, acc[2 * j + 1]);
        }
      }
    }
  }
  if constexpr (K2 > 0) {
    const float* x = X2 + (size_t)b * K2 * NL + n;
    for (int k = 0; k < K2; k += 4) {
      float4 wv[J];
#pragma unroll
      for (int j = 0; j < J; j++)
        wv[j] = *(const float4*)(w0 + (size_t)(8 * j) * K + K1 + k);
#pragma unroll
      for (int kk = 0; kk < 4; kk++) {
        float2 xv = *(const float2*)(x + (size_t)(k + kk) * NL);
#pragma unroll
        for (int j = 0; j < J; j++) {
          float wk = reinterpret_cast<const float*>(&wv[j])[kk];
          acc[2 * j]     = fmaf(wk, xv.x, acc[2 * j]);
          acc[2 * j + 1] = fmaf(wk, xv.y, acc[2 * j + 1]);
        }
      }
    }
  }

#pragma unroll
  for (int j = 0; j < J; j++) {
    int o = obase + 8 * j;
    float r0 = acc[2 * j], r1 = acc[2 * j + 1];
    if (bias) {
      float bv = bias[o];
      r0 += bv; r1 += bv;
    }
    if constexpr (BN) {
      float s  = gamma[o] * rsqrtf(rvar[o] + 1e-5f);
      float sh = beta[o] - rmean[o] * s;
      r0 = fmaxf(fmaf(r0, s, sh), 0.f);
      r1 = fmaxf(fmaf(r1, s, sh), 0.f);
    }
    if constexpr (TR) {
      Y[((size_t)b * NL + n) * M + o]     = r0;
      Y[((size_t)b * NL + n + 1) * M + o] = r1;
    } else {
      float2 out2 = {r0, r1};
      *(float2*)(Y + ((size_t)b * M + o) * NL + n) = out2;
    }
  }
}

// ---------------------------------------------------------------------------
// Deformable point-sampling attention. One wave per query.
// q_t [B][N][16], k_t [B][N][16], v_t [B][N][128], off_t [B][N][64]
// out [B][128][N] channel-major.
// ---------------------------------------------------------------------------
__global__ __launch_bounds__(256) void attn_k(
    const float* __restrict__ q_t, const float* __restrict__ k_t,
    const float* __restrict__ v_t, const float* __restrict__ off_t,
    float* __restrict__ out) {
  const int lane = threadIdx.x;                // 0..63
  const int wav  = threadIdx.y;                // 0..3
  const int qidx = blockIdx.x * 4 + wav;       // 0..8191
  const int b = qidx >> 12;
  const int n = qidx & (NL - 1);
  const int qy = n >> 6, qx = n & 63;

  __shared__ float s_a[4][32];
  __shared__ float s_w[4][32][4];
  __shared__ int   s_i[4][32][4];

  // q for this query (uniform across lanes, broadcast loads)
  const float* qp = q_t + ((size_t)b * NL + n) * 16;
  float qreg[16];
#pragma unroll
  for (int i = 0; i < 16; i += 4) {
    float4 t = *(const float4*)(qp + i);
    qreg[i] = t.x; qreg[i + 1] = t.y; qreg[i + 2] = t.z; qreg[i + 3] = t.w;
  }

  const int p = lane >> 1;
  const int h = lane & 1;
  float2 dxy = *(const float2*)(off_t + ((size_t)b * NL + n) * 64 + 2 * p);
  float sx = (float)qx + dxy.x;
  float sy = (float)qy + dxy.y;
  float x0f = floorf(sx), y0f = floorf(sy);
  float wx = sx - x0f, wy = sy - y0f;
  int x0i = (int)x0f, y0i = (int)y0f;
  int x0 = min(63, max(0, x0i)), x1 = min(63, max(0, x0i + 1));
  int y0 = min(63, max(0, y0i)), y1 = min(63, max(0, y0i + 1));

  // this lane handles one y-row (2 taps) of the bilinear stencil
  int   yr  = h ? y1 : y0;
  float wyr = h ? wy : (1.f - wy);
  int   pa = yr * 64 + x0, pb = yr * 64 + x1;
  float wa = wyr * (1.f - wx), wb = wyr * wx;

  const float* kb = k_t + (size_t)b * NL * 16;
  float da = 0.f, db = 0.f;
  {
    const float* ka = kb + (size_t)pa * 16;
    const float* kc = kb + (size_t)pb * 16;
#pragma unroll
    for (int i = 0; i < 16; i += 4) {
      float4 a4 = *(const float4*)(ka + i);
      float4 c4 = *(const float4*)(kc + i);
      da = fmaf(qreg[i], a4.x, da); da = fmaf(qreg[i + 1], a4.y, da);
      da = fmaf(qreg[i + 2], a4.z, da); da = fmaf(qreg[i + 3], a4.w, da);
      db = fmaf(qreg[i], c4.x, db); db = fmaf(qreg[i + 1], c4.y, db);
      db = fmaf(qreg[i + 2], c4.z, db); db = fmaf(qreg[i + 3], c4.w, db);
    }
  }
  float part = wa * da + wb * db;
  part += __shfl_xor(part, 1, 64);             // both lanes of pair get full logit
  float logit = part * 0.25f;                  // / sqrt(16)

  // softmax over 32 points (each value duplicated in 2 lanes)
  float m = logit;
#pragma unroll
  for (int s = 32; s > 0; s >>= 1) m = fmaxf(m, __shfl_xor(m, s, 64));
  float e = __expf(logit - m);
  float ssum = e;
#pragma unroll
  for (int s = 32; s > 0; s >>= 1) ssum += __shfl_xor(ssum, s, 64);
  float a = e * 2.f / ssum;                    // ssum counts each point twice

  s_w[wav][p][2 * h + 0] = wa;
  s_w[wav][p][2 * h + 1] = wb;
  s_i[wav][p][2 * h + 0] = pa;
  s_i[wav][p][2 * h + 1] = pb;
  if (h == 0) s_a[wav][p] = a;
  __syncthreads();

  // output accumulation: lane owns channels c=2*lane, 2*lane+1
  const float* vb = v_t + (size_t)b * NL * 128;
  const int c = 2 * lane;
  float o0 = 0.f, o1 = 0.f;
  for (int pp = 0; pp < 32; pp++) {
    float ap = s_a[wav][pp];
    float a0 = 0.f, a1 = 0.f;
#pragma unroll
    for (int t = 0; t < 4; t++) {
      float w  = s_w[wav][pp][t];
      int  pix = s_i[wav][pp][t];
      float2 vv = *(const float2*)(vb + (size_t)pix * 128 + c);
      a0 = fmaf(w, vv.x, a0);
      a1 = fmaf(w, vv.y, a1);
    }
    o0 = fmaf(ap, a0, o0);
    o1 = fmaf(ap, a1, o1);
  }
  out[((size_t)b * 128 + c) * NL + n]     = o0;
  out[((size_t)b * 128 + c + 1) * NL + n] = o1;
}

// ---------------------------------------------------------------------------
extern "C" void kernel_launch(void* const* d_in, const int* in_sizes, int n_in,
                              void* d_out, int out_size, void* d_ws, size_t ws_size,
                              hipStream_t stream) {
  const float* low   = (const float*)d_in[0];
  const float* high  = (const float*)d_in[1];
  const float* W1    = (const float*)d_in[2];
  const float* b1    = (const float*)d_in[3];
  const float* W2    = (const float*)d_in[4];
  const float* b2    = (const float*)d_in[5];
  const float* Wq    = (const float*)d_in[6];
  const float* bq    = (const float*)d_in[7];
  const float* Wk    = (const float*)d_in[8];
  const float* bk    = (const float*)d_in[9];
  const float* Wv    = (const float*)d_in[10];
  const float* bv    = (const float*)d_in[11];
  const float* Woff  = (const float*)d_in[12];
  const float* boff  = (const float*)d_in[13];
  const float* Wb    = (const float*)d_in[14];
  const float* gamma = (const float*)d_in[15];
  const float* beta  = (const float*)d_in[16];
  const float* rmean = (const float*)d_in[17];
  const float* rvar  = (const float*)d_in[18];
  float* out = (float*)d_out;

  float* ws      = (float*)d_ws;
  float* high_up = ws;                     // [2][256][4096] = 2,097,152
  float* qf      = high_up + 2097152;      // [2][128][4096] = 1,048,576
  float* vf      = qf + 1048576;           // [2][128][4096]
  float* q_t     = vf + 1048576;           // [2][4096][16]  =   131,072
  float* k_t     = q_t + 131072;           // [2][4096][16]
  float* off_t   = k_t + 131072;           // [2][4096][64]  =   524,288
  float* v_t     = off_t + 524288;         // [2][4096][128] = 1,048,576
  float* attn    = v_t + 1048576;          // [2][128][4096] = 1,048,576

  dim3 gblk(32, 8);

  upsample_k<<<8192, 256, 0, stream>>>(high, high_up);

  // query_feature = W1 @ [high_up; low] + b1   -> qf [B][128][N]
  gemm_k<128, 256, 256, 64, false, false><<<dim3(128, 2), gblk, 0, stream>>>(
      W1, b1, high_up, low, qf, nullptr, nullptr, nullptr, nullptr);
  // value_feature = W2 @ high_up + b2          -> vf [B][128][N]
  gemm_k<128, 256, 0, 64, false, false><<<dim3(128, 2), gblk, 0, stream>>>(
      W2, b2, high_up, nullptr, vf, nullptr, nullptr, nullptr, nullptr);
  // q = Wq @ qf + bq      (pixel-major)
  gemm_k<16, 128, 0, 16, false, true><<<dim3(128, 1), gblk, 0, stream>>>(
      Wq, bq, qf, nullptr, q_t, nullptr, nullptr, nullptr, nullptr);
  // k = Wk @ vf + bk      (pixel-major)
  gemm_k<16, 128, 0, 16, false, true><<<dim3(128, 1), gblk, 0, stream>>>(
      Wk, bk, vf, nullptr, k_t, nullptr, nullptr, nullptr, nullptr);
  // off = Woff @ qf + boff (pixel-major)
  gemm_k<64, 128, 0, 64, false, true><<<dim3(128, 1), gblk, 0, stream>>>(
      Woff, boff, qf, nullptr, off_t, nullptr, nullptr, nullptr, nullptr);
  // v = Wv @ vf + bv      (pixel-major)
  gemm_k<128, 128, 0, 64, false, true><<<dim3(128, 2), gblk, 0, stream>>>(
      Wv, bv, vf, nullptr, v_t, nullptr, nullptr, nullptr, nullptr);

  // deformable attention -> attn [B][128][N]
  attn_k<<<2048, dim3(64, 4), 0, stream>>>(q_t, k_t, v_t, off_t, attn);

  // final: Wb @ [attn; high_up], BN + ReLU -> d_out
  gemm_k<256, 128, 256, 64, true, false><<<dim3(128, 4), gblk, 0, stream>>>(
      Wb, nullptr, attn, high_up, out, gamma, beta, rmean, rvar);
}

// Round 2
// 173.800 us; speedup vs baseline: 2.3511x; 2.3511x over previous
//
#include <hip/hip_runtime.h>
#include <hip/hip_bf16.h>

#define NL 4096   // 64*64 low-res pixels
#define HH 32
#define WH 32

typedef __attribute__((ext_vector_type(8))) short s8v;   // 8 bf16 (4 VGPRs) MFMA A/B frag
typedef __attribute__((ext_vector_type(4))) short s4v;   // 4 bf16 (8B)
typedef __attribute__((ext_vector_type(4))) float f32x4; // MFMA C/D frag

static __device__ inline unsigned short f2bf(float x) {
  __hip_bfloat16 h = __float2bfloat16(x);   // RNE
  return *reinterpret_cast<unsigned short*>(&h);
}
static __device__ inline float bfbits2f(unsigned int lo16) {
  unsigned int u = lo16 << 16;
  return *reinterpret_cast<float*>(&u);
}

// ---------------------------------------------------------------------------
// Bilinear 2x upsample (half-pixel, border-clamped), fp32 channel-major
// [B,256,32,32] -> [B,256,64,64]
// ---------------------------------------------------------------------------
__global__ __launch_bounds__(256) void upsample_k(const float* __restrict__ hf,
                                                  float* __restrict__ hu) {
  int idx = blockIdx.x * 256 + threadIdx.x;   // over 2*256*4096
  int n  = idx & (NL - 1);
  int bc = idx >> 12;
  int y = n >> 6, x = n & 63;
  float sx = x * 0.5f - 0.25f;
  float sy = y * 0.5f - 0.25f;
  float x0f = floorf(sx), y0f = floorf(sy);
  float wx = sx - x0f, wy = sy - y0f;
  int x0 = (int)x0f, y0 = (int)y0f;
  int x0c = min(WH - 1, max(0, x0)), x1c = min(WH - 1, max(0, x0 + 1));
  int y0c = min(HH - 1, max(0, y0)), y1c = min(HH - 1, max(0, y0 + 1));
  const float* f = hf + (size_t)bc * (HH * WH);
  float v00 = f[y0c * WH + x0c], v01 = f[y0c * WH + x1c];
  float v10 = f[y1c * WH + x0c], v11 = f[y1c * WH + x1c];
  hu[idx] = (1.f - wy) * ((1.f - wx) * v00 + wx * v01)
          +        wy  * ((1.f - wx) * v10 + wx * v11);
}

// ---------------------------------------------------------------------------
// Weight fp32 -> bf16 (all weights packed into one buffer, fixed offsets)
// W1 65536 | W2 32768 | Wq 2048 | Wk 2048 | Wv 16384 | Woff 8192 | Wb 98304
// ---------------------------------------------------------------------------
__global__ __launch_bounds__(256) void convert_weights_k(
    const float* __restrict__ w1, const float* __restrict__ w2,
    const float* __restrict__ wq, const float* __restrict__ wk,
    const float* __restrict__ wv, const float* __restrict__ woff,
    const float* __restrict__ wb, short* __restrict__ dst) {
  int i = blockIdx.x * 256 + threadIdx.x;
  const float* src; int off;
  if      (i <  65536) { src = w1;   off = 0; }
  else if (i <  98304) { src = w2;   off = 65536; }
  else if (i < 100352) { src = wq;   off = 98304; }
  else if (i < 102400) { src = wk;   off = 100352; }
  else if (i < 118784) { src = wv;   off = 102400; }
  else if (i < 126976) { src = woff; off = 118784; }
  else if (i < 225280) { src = wb;   off = 126976; }
  else return;
  dst[i] = (short)f2bf(src[i - off]);
}

// ---------------------------------------------------------------------------
// Transpose fp32 channel-major [b][256][4096] -> bf16 pixel-major xin[b][n][512]
// blockIdx.z: b*2 + (0:high_up -> cols 0..255, 1:low -> cols 256..511)
// ---------------------------------------------------------------------------
__global__ __launch_bounds__(256) void transpose_k(const float* __restrict__ hu,
                                                   const float* __restrict__ low,
                                                   short* __restrict__ xin) {
  int b = blockIdx.z >> 1, s = blockIdx.z & 1;
  const float* src = (s ? low : hu) + (size_t)b * 256 * NL;
  int n0 = blockIdx.x * 64, c0 = blockIdx.y * 64;
  __shared__ short lds[64][65];
  int nl = threadIdx.x & 63, cl = threadIdx.x >> 6;
#pragma unroll
  for (int i = 0; i < 16; i++) {
    int c = c0 + cl + 4 * i;
    lds[nl][cl + 4 * i] = (short)f2bf(src[(size_t)c * NL + n0 + nl]);
  }
  __syncthreads();
  int cc = threadIdx.x & 63, nr = threadIdx.x >> 6;
#pragma unroll
  for (int i = 0; i < 16; i++) {
    int n = n0 + nr + 4 * i;
    xin[((size_t)b * NL + n) * 512 + s * 256 + c0 + cc] = lds[nr + 4 * i][cc];
  }
}

// ---------------------------------------------------------------------------
// MFMA GEMM: Y[n][o] (or channel-major) = sum_k W[o][k] * X[n][k]
// W bf16 [M][K1+K2] row-major. B1/B2 bf16 pixel-major, row strides sB1/sB2.
// Wave tile (MF*16) x 32; block = 4 waves stacked over n (128 n/block).
// MODE 0: bf16 pixel-major + bias | 1: f32 pixel-major + bias
// MODE 2: f32 channel-major [b][M][4096] + BN + ReLU
// ---------------------------------------------------------------------------
template <int M, int K1, int K2, int MF, int MODE>
__global__ __launch_bounds__(256) void mfma_gemm(
    const short* __restrict__ W, const float* __restrict__ bias,
    const short* __restrict__ B1, int sB1,
    const short* __restrict__ B2, int sB2,
    void* __restrict__ Yv,
    const float* __restrict__ gamma, const float* __restrict__ beta,
    const float* __restrict__ rmean, const float* __restrict__ rvar) {
  constexpr int K = K1 + K2;
  const int tid = threadIdx.x;
  const int wave = tid >> 6, lane = tid & 63;
  const int quad = lane >> 4, id = lane & 15;
  const int n0 = blockIdx.x * 128 + wave * 32;
  const int m0 = blockIdx.y * (MF * 16);

  f32x4 acc[MF][2];
#pragma unroll
  for (int mf = 0; mf < MF; mf++)
#pragma unroll
    for (int nf = 0; nf < 2; nf++) acc[mf][nf] = (f32x4){0.f, 0.f, 0.f, 0.f};

  const short* aptr[MF];
#pragma unroll
  for (int mf = 0; mf < MF; mf++)
    aptr[mf] = W + (size_t)(m0 + mf * 16 + id) * K + quad * 8;
  const short* bptr[2];
#pragma unroll
  for (int nf = 0; nf < 2; nf++)
    bptr[nf] = B1 + (size_t)(n0 + nf * 16 + id) * sB1 + quad * 8;

#pragma unroll
  for (int kk = 0; kk < K1; kk += 32) {
    s8v a[MF], b[2];
#pragma unroll
    for (int mf = 0; mf < MF; mf++) a[mf] = *(const s8v*)(aptr[mf] + kk);
#pragma unroll
    for (int nf = 0; nf < 2; nf++) b[nf] = *(const s8v*)(bptr[nf] + kk);
#pragma unroll
    for (int mf = 0; mf < MF; mf++)
#pragma unroll
      for (int nf = 0; nf < 2; nf++)
        acc[mf][nf] = __builtin_amdgcn_mfma_f32_16x16x32_bf16(
            a[mf], b[nf], acc[mf][nf], 0, 0, 0);
  }
  if constexpr (K2 > 0) {
    const short* bptr2[2];
#pragma unroll
    for (int nf = 0; nf < 2; nf++)
      bptr2[nf] = B2 + (size_t)(n0 + nf * 16 + id) * sB2 + quad * 8;
#pragma unroll
    for (int kk = 0; kk < K2; kk += 32) {
      s8v a[MF], b[2];
#pragma unroll
      for (int mf = 0; mf < MF; mf++) a[mf] = *(const s8v*)(aptr[mf] + K1 + kk);
#pragma unroll
      for (int nf = 0; nf < 2; nf++) b[nf] = *(const s8v*)(bptr2[nf] + kk);
#pragma unroll
      for (int mf = 0; mf < MF; mf++)
#pragma unroll
        for (int nf = 0; nf < 2; nf++)
          acc[mf][nf] = __builtin_amdgcn_mfma_f32_16x16x32_bf16(
              a[mf], b[nf], acc[mf][nf], 0, 0, 0);
    }
  }

#pragma unroll
  for (int mf = 0; mf < MF; mf++) {
#pragma unroll
    for (int nf = 0; nf < 2; nf++) {
      int n = n0 + nf * 16 + id;
      int mbase = m0 + mf * 16 + quad * 4;
      f32x4 v = acc[mf][nf];
      if (bias) {
#pragma unroll
        for (int r = 0; r < 4; r++) v[r] += bias[mbase + r];
      }
      if constexpr (MODE == 0) {
        s4v o;
#pragma unroll
        for (int r = 0; r < 4; r++) o[r] = (short)f2bf(v[r]);
        *(s4v*)((short*)Yv + (size_t)n * M + mbase) = o;
      } else if constexpr (MODE == 1) {
        *(f32x4*)((float*)Yv + (size_t)n * M + mbase) = v;
      } else {
        int b = n >> 12, nlow = n & (NL - 1);
#pragma unroll
        for (int r = 0; r < 4; r++) {
          int o = mbase + r;
          float s  = gamma[o] * rsqrtf(rvar[o] + 1e-5f);
          float sh = beta[o] - rmean[o] * s;
          ((float*)Yv)[((size_t)b * M + o) * NL + nlow] =
              fmaxf(fmaf(v[r], s, sh), 0.f);
        }
      }
    }
  }
}

// ---------------------------------------------------------------------------
// Deformable point-sampling attention. One wave per query.
// q_t/k_t [b][n][16] f32, off_t [b][n][64] f32, v_t [b][n][128] bf16
// out attn_t [b][n][128] bf16 pixel-major
// ---------------------------------------------------------------------------
__global__ __launch_bounds__(256) void attn_k(
    const float* __restrict__ q_t, const float* __restrict__ k_t,
    const short* __restrict__ v_t, const float* __restrict__ off_t,
    short* __restrict__ out) {
  const int lane = threadIdx.x;                // 0..63
  const int wav  = threadIdx.y;                // 0..3
  const int qidx = blockIdx.x * 4 + wav;
  const int b = qidx >> 12;
  const int n = qidx & (NL - 1);
  const int qy = n >> 6, qx = n & 63;

  __shared__ float s_a[4][32];
  __shared__ float s_w[4][32][4];
  __shared__ int   s_i[4][32][4];

  const float* qp = q_t + ((size_t)b * NL + n) * 16;
  float qreg[16];
#pragma unroll
  for (int i = 0; i < 16; i += 4) {
    float4 t = *(const float4*)(qp + i);
    qreg[i] = t.x; qreg[i + 1] = t.y; qreg[i + 2] = t.z; qreg[i + 3] = t.w;
  }

  const int p = lane >> 1;
  const int h = lane & 1;
  float2 dxy = *(const float2*)(off_t + ((size_t)b * NL + n) * 64 + 2 * p);
  float sx = (float)qx + dxy.x;
  float sy = (float)qy + dxy.y;
  float x0f = floorf(sx), y0f = floorf(sy);
  float wx = sx - x0f, wy = sy - y0f;
  int x0i = (int)x0f, y0i = (int)y0f;
  int x0 = min(63, max(0, x0i)), x1 = min(63, max(0, x0i + 1));
  int y0 = min(63, max(0, y0i)), y1 = min(63, max(0, y0i + 1));

  int   yr  = h ? y1 : y0;
  float wyr = h ? wy : (1.f - wy);
  int   pa = yr * 64 + x0, pb = yr * 64 + x1;
  float wa = wyr * (1.f - wx), wb = wyr * wx;

  const float* kb = k_t + (size_t)b * NL * 16;
  float da = 0.f, db = 0.f;
  {
    const float* ka = kb + (size_t)pa * 16;
    const float* kc = kb + (size_t)pb * 16;
#pragma unroll
    for (int i = 0; i < 16; i += 4) {
      float4 a4 = *(const float4*)(ka + i);
      float4 c4 = *(const float4*)(kc + i);
      da = fmaf(qreg[i], a4.x, da); da = fmaf(qreg[i + 1], a4.y, da);
      da = fmaf(qreg[i + 2], a4.z, da); da = fmaf(qreg[i + 3], a4.w, da);
      db = fmaf(qreg[i], c4.x, db); db = fmaf(qreg[i + 1], c4.y, db);
      db = fmaf(qreg[i + 2], c4.z, db); db = fmaf(qreg[i + 3], c4.w, db);
    }
  }
  float part = wa * da + wb * db;
  part += __shfl_xor(part, 1, 64);
  float logit = part * 0.25f;

  float m = logit;
#pragma unroll
  for (int s = 32; s > 0; s >>= 1) m = fmaxf(m, __shfl_xor(m, s, 64));
  float e = __expf(logit - m);
  float ssum = e;
#pragma unroll
  for (int s = 32; s > 0; s >>= 1) ssum += __shfl_xor(ssum, s, 64);
  float a = e * 2.f / ssum;

  s_w[wav][p][2 * h + 0] = wa;
  s_w[wav][p][2 * h + 1] = wb;
  s_i[wav][p][2 * h + 0] = pa;
  s_i[wav][p][2 * h + 1] = pb;
  if (h == 0) s_a[wav][p] = a;
  __syncthreads();

  const short* vb = v_t + (size_t)b * NL * 128;
  const int c = 2 * lane;
  float o0 = 0.f, o1 = 0.f;
  for (int pp = 0; pp < 32; pp++) {
    float ap = s_a[wav][pp];
    float a0 = 0.f, a1 = 0.f;
#pragma unroll
    for (int t = 0; t < 4; t++) {
      float w  = s_w[wav][pp][t];
      int  pix = s_i[wav][pp][t];
      unsigned int u = *(const unsigned int*)(vb + (size_t)pix * 128 + c);
      float v0 = bfbits2f(u & 0xffffu);
      float v1 = bfbits2f(u >> 16);
      a0 = fmaf(w, v0, a0);
      a1 = fmaf(w, v1, a1);
    }
    o0 = fmaf(ap, a0, o0);
    o1 = fmaf(ap, a1, o1);
  }
  unsigned int pk = (unsigned int)f2bf(o0) | ((unsigned int)f2bf(o1) << 16);
  *(unsigned int*)(out + ((size_t)b * NL + n) * 128 + c) = pk;
}

// ---------------------------------------------------------------------------
extern "C" void kernel_launch(void* const* d_in, const int* in_sizes, int n_in,
                              void* d_out, int out_size, void* d_ws, size_t ws_size,
                              hipStream_t stream) {
  const float* low   = (const float*)d_in[0];
  const float* high  = (const float*)d_in[1];
  const float* W1    = (const float*)d_in[2];
  const float* b1    = (const float*)d_in[3];
  const float* W2    = (const float*)d_in[4];
  const float* b2    = (const float*)d_in[5];
  const float* Wq    = (const float*)d_in[6];
  const float* bq    = (const float*)d_in[7];
  const float* Wk    = (const float*)d_in[8];
  const float* bk    = (const float*)d_in[9];
  const float* Wv    = (const float*)d_in[10];
  const float* bv    = (const float*)d_in[11];
  const float* Woff  = (const float*)d_in[12];
  const float* boff  = (const float*)d_in[13];
  const float* Wb    = (const float*)d_in[14];
  const float* gamma = (const float*)d_in[15];
  const float* beta  = (const float*)d_in[16];
  const float* rmean = (const float*)d_in[17];
  const float* rvar  = (const float*)d_in[18];
  float* out = (float*)d_out;

  // workspace layout
  float* high_up = (float*)d_ws;                 // 2,097,152 f
  short* xin     = (short*)(high_up + 2097152);  // [2][4096][512]  bf16
  short* qf_t    = xin + 4194304;                // [2][4096][128]  bf16
  short* vf_t    = qf_t + 1048576;               // [2][4096][128]  bf16
  short* v_t     = vf_t + 1048576;               // [2][4096][128]  bf16
  short* attn_t  = v_t + 1048576;                // [2][4096][128]  bf16
  short* wc      = attn_t + 1048576;             // 225,280 bf16
  float* q_t     = (float*)(wc + 225280);        // [2][4096][16]   f32
  float* k_t     = q_t + 131072;                 // [2][4096][16]   f32
  float* off_t   = k_t + 131072;                 // [2][4096][64]   f32

  const short* w1c   = wc;
  const short* w2c   = wc + 65536;
  const short* wqc   = wc + 98304;
  const short* wkc   = wc + 100352;
  const short* wvc   = wc + 102400;
  const short* woffc = wc + 118784;
  const short* wbc   = wc + 126976;

  convert_weights_k<<<880, 256, 0, stream>>>(W1, W2, Wq, Wk, Wv, Woff, Wb, wc);
  upsample_k<<<8192, 256, 0, stream>>>(high, high_up);
  transpose_k<<<dim3(64, 4, 4), 256, 0, stream>>>(high_up, low, xin);

  // qf = W1 @ [high_up; low] + b1  -> bf16 pixel-major
  mfma_gemm<128, 512, 0, 2, 0><<<dim3(64, 4), 256, 0, stream>>>(
      w1c, b1, xin, 512, nullptr, 0, qf_t, nullptr, nullptr, nullptr, nullptr);
  // vf = W2 @ high_up + b2
  mfma_gemm<128, 256, 0, 2, 0><<<dim3(64, 4), 256, 0, stream>>>(
      w2c, b2, xin, 512, nullptr, 0, vf_t, nullptr, nullptr, nullptr, nullptr);
  // q = Wq @ qf + bq  (f32 pixel-major)
  mfma_gemm<16, 128, 0, 1, 1><<<dim3(64, 1), 256, 0, stream>>>(
      wqc, bq, qf_t, 128, nullptr, 0, q_t, nullptr, nullptr, nullptr, nullptr);
  // k = Wk @ vf + bk
  mfma_gemm<16, 128, 0, 1, 1><<<dim3(64, 1), 256, 0, stream>>>(
      wkc, bk, vf_t, 128, nullptr, 0, k_t, nullptr, nullptr, nullptr, nullptr);
  // off = Woff @ qf + boff
  mfma_gemm<64, 128, 0, 2, 1><<<dim3(64, 2), 256, 0, stream>>>(
      woffc, boff, qf_t, 128, nullptr, 0, off_t, nullptr, nullptr, nullptr, nullptr);
  // v = Wv @ vf + bv  (bf16 pixel-major)
  mfma_gemm<128, 128, 0, 2, 0><<<dim3(64, 4), 256, 0, stream>>>(
      wvc, bv, vf_t, 128, nullptr, 0, v_t, nullptr, nullptr, nullptr, nullptr);

  attn_k<<<2048, dim3(64, 4), 0, stream>>>(q_t, k_t, v_t, off_t, attn_t);

  // out = BN(ReLU) of Wb @ [attn; high_up]  (f32 channel-major)
  mfma_gemm<256, 128, 256, 2, 2><<<dim3(64, 8), 256, 0, stream>>>(
      wbc, nullptr, attn_t, 128, xin, 512, out, gamma, beta, rmean, rvar);
}